// Round 8
// baseline (275.695 us; speedup 1.0000x reference)
//
#include <hip/hip_runtime.h>
#include <math.h>

#define NTOK 32768
#define DIM  1024
#define NE   7
#define TROW 448   // T_all row width (DP-prefix padded), bf16

// ws layout (4-byte units up to B16; AIMG/TALL byte offsets). ws ~512 MB.
#define PN_OFF   0        // 7*1024 normalized prototypes (f32)
#define R1_OFF   7168
#define R2_OFF   7176
#define R3_OFF   7184
#define CNT_OFF  7192     // 8 ints
#define PR1_OFF  7200     // 1024*8
#define PR2_OFF  23584    // 128*8
#define PR3_OFF  24608    // 128*8
#define E0_OFF   25632    // NTOK*8 exp(sim/kappa)
#define LG_OFF   287776   // NTOK: log(top-1 gate)
#define LIST_OFF 320544   // NE*NTOK ints
#define B16_OFF  754720   // bf16 B weights (padded cols)
#define AIMG_OFF_BYTES 3936384   // LDS-image A: 32 chunks * 32768 B = 1 MB
#define TALL_OFF_BYTES 4984960   // bf16 T_all [NTOK][448] = 29.4 MB
#define NBLK 2055

#define SEPS 1e-6f

typedef __attribute__((ext_vector_type(8))) short short8v;
typedef __attribute__((ext_vector_type(4))) float f32x4;

// per-expert geometry
constexpr int DV[7]   = {8, 16, 32, 48, 64, 96, 128};
constexpr int DPV[7]  = {32, 32, 32, 64, 64, 96, 128};   // K-padded
constexpr int DAPV[7] = {16, 16, 32, 48, 64, 96, 128};   // N-padded
constexpr int BOV[7]  = {0, 32768, 65536, 98304, 163840, 229376, 327680};
constexpr int APRE[7] = {0, 32, 64, 96, 160, 224, 320};  // DP-prefix col in T_all
constexpr int RSV[7]  = {0, 16, 32, 64, 112, 176, 272};  // DAP-prefix row in A-image
// T_all column base of global A-tile t (A rows 16t..16t+15), t = 0..24
constexpr int TCOL[25] = {0, 32, 64, 80, 96, 112, 128, 160, 176, 192, 208,
                          224, 240, 256, 272, 288, 304,
                          320, 336, 352, 368, 384, 400, 416, 432};
constexpr int TS4[4] = {0, 7, 13, 19};   // tile quarters per nh-wave
constexpr int TN4[4] = {7, 6, 6, 6};

struct ExpPtrs { const float* A[NE]; const float* B[NE]; };

__device__ __forceinline__ short f2bf(float f) {
  union { float f; unsigned u; } v; v.f = f;
  return (short)((v.u + 0x7FFFu + ((v.u >> 16) & 1u)) >> 16);  // RNE
}

__device__ __forceinline__ float wsum(float v) {
  #pragma unroll
  for (int off = 32; off > 0; off >>= 1) v += __shfl_xor(v, off);
  return v;
}

__device__ __forceinline__ float dot4acc(float4 a, float4 b, float acc) {
  acc = fmaf(a.x, b.x, acc);
  acc = fmaf(a.y, b.y, acc);
  acc = fmaf(a.z, b.z, acc);
  acc = fmaf(a.w, b.w, acc);
  return acc;
}

__device__ __forceinline__ void gload_lds16(const void* g, void* l) {
  __builtin_amdgcn_global_load_lds(
      (const __attribute__((address_space(1))) unsigned int*)g,
      (__attribute__((address_space(3))) unsigned int*)l, 16, 0, 0);
}

// ---------------- K0: weights -> AIMG (LDS-image) + B16; proto prep ----------------
__global__ __launch_bounds__(256) void k_conv(ExpPtrs p, short* __restrict__ AIMG,
                                              short* __restrict__ B16,
                                              const float* __restrict__ proto,
                                              float* __restrict__ wsf,
                                              int* __restrict__ counts) {
  const int e = blockIdx.y;
  const int tid = threadIdx.x;
  const int d = DV[e], dp = DPV[e], dap = DAPV[e], bo = BOV[e], rs = RSV[e];

  if (blockIdx.x == 0) {
    __shared__ float pred[4];
    if (e == 0 && tid < 8) counts[tid] = 0;
    const int w = tid >> 6, lane = tid & 63;
    float v4[4], ss = 0.f;
    #pragma unroll
    for (int i = 0; i < 4; ++i) {
      v4[i] = proto[e * DIM + tid + 256 * i];
      ss = fmaf(v4[i], v4[i], ss);
    }
    ss = wsum(ss);
    if (lane == 0) pred[w] = ss;
    __syncthreads();
    float tot = ((pred[0] + pred[1]) + pred[2]) + pred[3];
    float inv = 1.f / fmaxf(sqrtf(tot), 1e-12f);
    #pragma unroll
    for (int i = 0; i < 4; ++i)
      wsf[PN_OFF + e * DIM + tid + 256 * i] = v4[i] * inv;
  }

  const float* A = p.A[e];
  const float* B = p.B[e];
  const int t0 = blockIdx.x * 256 + tid;

  // A-image: AIMG[c][row][q] q<4 = bf16x8 of A[row][c*32+q*8..], q==4 = pad
  const int tot = dap * 160;  // 32 chunks * 5 q per row
  for (int i = t0; i < tot; i += 16 * 256) {
    int lr = i / 160, rem = i - lr * 160;
    int c = rem / 5, q = rem - c * 5;
    short8v v = (short8v){0, 0, 0, 0, 0, 0, 0, 0};
    if (q < 4 && lr < d) {
      const float* src = A + (size_t)lr * DIM + c * 32 + q * 8;
      #pragma unroll
      for (int j = 0; j < 8; ++j) v[j] = f2bf(src[j]);
    }
    *(short8v*)&AIMG[c * 16384 + (rs + lr) * 40 + q * 8] = v;
  }
  if (e == 0) {  // zero the per-chunk junk tail [32000,32768)
    for (int i = t0; i < 32 * 48; i += 16 * 256) {
      int c = i / 48, qq = i - c * 48;
      *(short8v*)&AIMG[c * 16384 + 16000 + qq * 8] = (short8v){0,0,0,0,0,0,0,0};
    }
  }

  short* Bd = B16 + bo;
  for (int i = t0; i < DIM * dp; i += 16 * 256) {
    int j = i / dp, r = i - j * dp;
    Bd[i] = (r < d) ? f2bf(B[(size_t)j * d + r]) : (short)0;
  }
}

// ---------------- K1: fused sim (f32) + T_all = x * A_all^T (bf16 MFMA) ----------------
// 1024 blocks x 512 thr; block = 32 tokens. Wave w: mh=w>>2 token-half (16 tok),
// nh=w&3 tile-quarter (TS4/TN4). A staged per 32-k chunk via global_load_lds from
// the pre-built AIMG image (pitch-40 rows: uniform 2-way banks = free).
// Sim: nh<3 waves accumulate experts {2nh,2nh+1}; nh==3 wave: expert 6 + |x|^2.
__global__ __launch_bounds__(512, 6) void k_simT(const float* __restrict__ x,
                                                 const short* __restrict__ AIMG,
                                                 const float* __restrict__ wsf,
                                                 float* __restrict__ e0,
                                                 float* __restrict__ pr1,
                                                 short* __restrict__ Tall) {
  __shared__ __align__(16) short As[16384];   // 32768 B (one chunk image)
  __shared__ float pnS[7][32];
  __shared__ float simS[2][16][8];
  const int tid = threadIdx.x;
  const int n0 = blockIdx.x * 32;
  const int w = tid >> 6, lane = tid & 63, lo = lane & 15, hi = lane >> 4;
  const int mh = w >> 2, nh = w & 3;
  const int tokBase = n0 + mh * 16;
  const int ts = TS4[nh], tn = TN4[nh];
  const int eA = 2 * nh;
  const bool pnT = tid < 224;

  // zero Tall pad cols (e0:[16,32) e1:[48,64) e3:[144,160)) for this block's rows
  for (int i = tid; i < 32 * 48; i += 512) {
    int r = i / 48, c = i - r * 48;
    int col = (c < 16) ? (16 + c) : ((c < 32) ? (32 + c) : (112 + c));
    Tall[(size_t)(n0 + r) * TROW + col] = 0;
  }

  const float* xp = x + (size_t)(tokBase + lo) * DIM;
  const float* PN = wsf + PN_OFF;
  const char* gA = (const char*)AIMG;

  f32x4 acc[7];
  #pragma unroll
  for (int t = 0; t < 7; ++t) acc[t] = (f32x4){0.f, 0.f, 0.f, 0.f};
  float dkA = 0.f, dkB = 0.f, xx = 0.f;

  // prologue: stage chunk 0
  #pragma unroll
  for (int cc = 0; cc < 4; ++cc) {
    int call = w * 4 + cc;
    gload_lds16(gA + call * 1024 + lane * 16, (char*)As + call * 1024);
  }
  if (pnT) pnS[tid >> 5][tid & 31] = PN[(tid >> 5) * DIM + (tid & 31)];
  float4 nx0 = *(const float4*)(xp + hi * 8);
  float4 nx1 = *(const float4*)(xp + hi * 8 + 4);
  __syncthreads();  // drains vmcnt -> As/pnS chunk 0 ready

  for (int c = 0; c < 32; ++c) {
    float4 x0 = nx0, x1 = nx1;
    float pv = 0.f;
    if (c < 31) {
      nx0 = *(const float4*)(xp + (c + 1) * 32 + hi * 8);
      nx1 = *(const float4*)(xp + (c + 1) * 32 + hi * 8 + 4);
      if (pnT) pv = PN[(tid >> 5) * DIM + (c + 1) * 32 + (tid & 31)];
    }
    short8v af;
    af[0] = f2bf(x0.x); af[1] = f2bf(x0.y); af[2] = f2bf(x0.z); af[3] = f2bf(x0.w);
    af[4] = f2bf(x1.x); af[5] = f2bf(x1.y); af[6] = f2bf(x1.z); af[7] = f2bf(x1.w);

    {  // sim partials (balanced across nh)
      float4 pa0 = *(const float4*)&pnS[eA][hi * 8];
      float4 pa1 = *(const float4*)&pnS[eA][hi * 8 + 4];
      dkA = dot4acc(x0, pa0, dot4acc(x1, pa1, dkA));
      if (nh < 3) {
        float4 pb0 = *(const float4*)&pnS[eA + 1][hi * 8];
        float4 pb1 = *(const float4*)&pnS[eA + 1][hi * 8 + 4];
        dkB = dot4acc(x0, pb0, dot4acc(x1, pb1, dkB));
      } else {
        xx = dot4acc(x0, x0, dot4acc(x1, x1, xx));
      }
    }
    #pragma unroll
    for (int tt = 0; tt < 7; ++tt) {
      if (tt < tn) {
        short8v bf = *(const short8v*)&As[(16 * (ts + tt) + lo) * 40 + hi * 8];
        acc[tt] = __builtin_amdgcn_mfma_f32_16x16x32_bf16(af, bf, acc[tt], 0, 0, 0);
      }
    }
    __syncthreads();  // all reads of As/pnS chunk c done
    if (c < 31) {
      #pragma unroll
      for (int cc = 0; cc < 4; ++cc) {
        int call = w * 4 + cc;
        gload_lds16(gA + (size_t)(c + 1) * 32768 + call * 1024 + lane * 16,
                    (char*)As + call * 1024);
      }
      if (pnT) pnS[tid >> 5][tid & 31] = pv;
      __syncthreads();  // chunk c+1 landed (barrier drains vmcnt)
    }
  }

  // T_all write (C layout: token = hi*4+j, col = TCOL[tile] + lo)
  #pragma unroll
  for (int tt = 0; tt < 7; ++tt) {
    if (tt < tn) {
      int col = TCOL[ts + tt] + lo;
      #pragma unroll
      for (int j = 0; j < 4; ++j)
        Tall[(size_t)(tokBase + hi * 4 + j) * TROW + col] = f2bf(acc[tt][j]);
    }
  }

  // sim epilogue
  dkA += __shfl_xor(dkA, 16); dkA += __shfl_xor(dkA, 32);
  if (nh < 3) { dkB += __shfl_xor(dkB, 16); dkB += __shfl_xor(dkB, 32); }
  else        { xx  += __shfl_xor(xx, 16);  xx  += __shfl_xor(xx, 32); }
  if (hi == 0) {
    simS[mh][lo][eA] = dkA;
    if (nh < 3) simS[mh][lo][eA + 1] = dkB;
    else        simS[mh][lo][7] = xx;
  }
  __syncthreads();
  if (tid < 32) {
    int m2 = tid >> 4, t2 = tid & 15;
    int n = n0 + m2 * 16 + t2;
    float xv = simS[m2][t2][7];
    float nrm = fmaxf(sqrtf(xv), 1e-12f);
    float ev[8];
    #pragma unroll
    for (int k = 0; k < 7; ++k) ev[k] = expf((simS[m2][t2][k] / nrm) / 0.1f);
    ev[7] = 0.f;
    *(float4*)&e0[(size_t)n * 8]     = make_float4(ev[0], ev[1], ev[2], ev[3]);
    *(float4*)&e0[(size_t)n * 8 + 4] = make_float4(ev[4], ev[5], ev[6], ev[7]);
    #pragma unroll
    for (int k = 0; k < 8; ++k) simS[m2][t2][k] = ev[k];
  }
  __syncthreads();
  if (tid < 8) {
    float s = 0.f;
    for (int m2 = 0; m2 < 2; ++m2)
      for (int t2 = 0; t2 < 16; ++t2) s += simS[m2][t2][tid];
    pr1[blockIdx.x * 8 + tid] = s;
  }
}

#define SUM7(l) (((((((l)[0] + (l)[1]) + (l)[2]) + (l)[3]) + (l)[4]) + (l)[5]) + (l)[6])

// ---------------- sinkhorn passes; each self-reduces prior partials ----------------
template<int DEPTH>
__global__ __launch_bounds__(256) void k_pass(const float* __restrict__ e0,
                                              float* __restrict__ wsf,
                                              const float* __restrict__ src, int nb,
                                              float* __restrict__ prOut,
                                              int* __restrict__ counts,
                                              int* __restrict__ list,
                                              float* __restrict__ lgv) {
  __shared__ float red2[8][33];
  __shared__ float Rcur[8];
  const int tid = threadIdx.x;
  {
    const int k = tid & 7, m = tid >> 3;
    float a = 0.f;
    for (int b = m; b < nb; b += 32) a += src[b * 8 + k];
    red2[k][m] = a;
    __syncthreads();
    if (tid < 8) {
      float s = 0.f;
      for (int mm = 0; mm < 32; ++mm) s += red2[tid][mm];
      Rcur[tid] = s;
      if (blockIdx.x == 0) {
        int roff = (DEPTH == 1) ? R1_OFF : (DEPTH == 2) ? R2_OFF : R3_OFF;
        wsf[roff + tid] = s;
      }
    }
    __syncthreads();
  }

  const int n = blockIdx.x * 256 + tid;
  float4 v0 = *(const float4*)(e0 + (size_t)n * 8);
  float4 v1 = *(const float4*)(e0 + (size_t)n * 8 + 4);
  float l[NE] = {v0.x, v0.y, v0.z, v0.w, v1.x, v1.y, v1.z};
  {
    const float* R1 = (DEPTH == 1) ? Rcur : (wsf + R1_OFF);
    #pragma unroll
    for (int k = 0; k < NE; ++k) l[k] = l[k] / (R1[k] + SEPS);
    float C = SUM7(l);
    #pragma unroll
    for (int k = 0; k < NE; ++k) l[k] = l[k] / (C + SEPS);
  }
  if constexpr (DEPTH >= 2) {
    const float* R2 = (DEPTH == 2) ? Rcur : (wsf + R2_OFF);
    #pragma unroll
    for (int k = 0; k < NE; ++k) l[k] = l[k] / (R2[k] + SEPS);
    float C = SUM7(l);
    #pragma unroll
    for (int k = 0; k < NE; ++k) l[k] = l[k] / (C + SEPS);
  }
  if constexpr (DEPTH >= 3) {
    const float* R3 = Rcur;
    #pragma unroll
    for (int k = 0; k < NE; ++k) l[k] = l[k] / (R3[k] + SEPS);
    float C = SUM7(l);
    #pragma unroll
    for (int k = 0; k < NE; ++k) l[k] = l[k] / (C + SEPS);
  }
  if constexpr (DEPTH == 3) {
    float best = l[0]; int be = 0;
    #pragma unroll
    for (int k = 1; k < NE; ++k) {
      if (l[k] > best) { best = l[k]; be = k; }
    }
    __shared__ int lcnt[8];
    __shared__ int wbase[4][8];
    __shared__ int gbase[8];
    const int w = tid >> 6, lane = tid & 63;
    if (tid < 8) lcnt[tid] = 0;
    __syncthreads();
    int rank = 0;
    #pragma unroll
    for (int k = 0; k < NE; ++k) {
      unsigned long long m = __ballot(be == k);
      if (lane == 0) wbase[w][k] = m ? atomicAdd(&lcnt[k], (int)__popcll(m)) : 0;
      if (be == k) rank = (int)__popcll(m & ((1ull << lane) - 1ull));
    }
    __syncthreads();
    if (tid < 8) gbase[tid] = lcnt[tid] ? atomicAdd(&counts[tid], lcnt[tid]) : 0;
    __syncthreads();
    int pos = gbase[be] + wbase[w][be] + rank;
    list[be * NTOK + pos] = n;
    lgv[n] = logf(best);
  } else {
    __shared__ float red[NE][256];
    #pragma unroll
    for (int k = 0; k < NE; ++k) red[k][tid] = l[k];
    __syncthreads();
    for (int off = 128; off > 0; off >>= 1) {
      if (tid < off) {
        #pragma unroll
        for (int k = 0; k < NE; ++k) red[k][tid] += red[k][tid + off];
      }
      __syncthreads();
    }
    if (tid < NE) prOut[blockIdx.x * 8 + tid] = red[tid][0];
  }
}

// ---------------- phase B: Y = T_all[tok, APRE_e..] * B^T + log(g) ----------------
__device__ __forceinline__ bool walk(int bid, const int* counts,
                                     int& e, int& tile, int& cnt) {
  int rem = bid; e = 0;
  while (true) {
    cnt = counts[e];
    int tiles = (cnt + 15) >> 4;
    if (rem < tiles) { tile = rem; return true; }
    rem -= tiles;
    if (++e == NE) return false;
  }
}

template<int E>
__device__ void phB_impl(const short* __restrict__ Bp,
                         const short* __restrict__ Tall,
                         const int* __restrict__ list_e,
                         const float* __restrict__ lg,
                         int cnt, int tile, float* __restrict__ out) {
  constexpr int DP = DPV[E];
  constexpr int KS2 = DP / 32;
  const int tid = threadIdx.x;
  const int w = tid >> 6, lane = tid & 63;
  const int lo = lane & 15, hi = lane >> 4;
  const int m0 = tile * 16;

  const int myTok = list_e[min(m0 + lo, cnt - 1)];
  short8v tf[KS2];
  #pragma unroll
  for (int ks = 0; ks < KS2; ++ks)
    tf[ks] = *(const short8v*)(Tall + (size_t)myTok * TROW + APRE[E] + ks * 32 + hi * 8);

  int tok[4]; float lgvr[4];
  #pragma unroll
  for (int j = 0; j < 4; ++j) {
    tok[j] = list_e[min(m0 + hi * 4 + j, cnt - 1)];
    lgvr[j] = lg[tok[j]];
  }

  const short* BpL = Bp + (size_t)(w * 256 + lo) * DP + hi * 8;
  #pragma unroll 1
  for (int nt = 0; nt < 16; ++nt) {
    f32x4 acc = (f32x4){0.f, 0.f, 0.f, 0.f};
    #pragma unroll
    for (int ks = 0; ks < KS2; ++ks) {
      short8v bf = *(const short8v*)(BpL + (size_t)nt * 16 * DP + ks * 32);
      acc = __builtin_amdgcn_mfma_f32_16x16x32_bf16(tf[ks], bf, acc, 0, 0, 0);
    }
    #pragma unroll
    for (int j = 0; j < 4; ++j)
      out[(size_t)tok[j] * DIM + w * 256 + nt * 16 + lo] = acc[j] + lgvr[j];
  }
}

__global__ __launch_bounds__(256, 8) void k_phB(const short* __restrict__ B16,
                                                const short* __restrict__ Tall,
                                                const int* __restrict__ list,
                                                const float* __restrict__ lg,
                                                const int* __restrict__ counts,
                                                float* __restrict__ out) {
  int bid = ((int)blockIdx.x * 1024) % NBLK;  // coprime stride: spread heavy experts
  int e, tile, cnt;
  if (!walk(bid, counts, e, tile, cnt)) return;
  switch (e) {
    case 0: phB_impl<0>(B16 + BOV[0], Tall, list + 0 * NTOK, lg, cnt, tile, out); break;
    case 1: phB_impl<1>(B16 + BOV[1], Tall, list + 1 * NTOK, lg, cnt, tile, out); break;
    case 2: phB_impl<2>(B16 + BOV[2], Tall, list + 2 * NTOK, lg, cnt, tile, out); break;
    case 3: phB_impl<3>(B16 + BOV[3], Tall, list + 3 * NTOK, lg, cnt, tile, out); break;
    case 4: phB_impl<4>(B16 + BOV[4], Tall, list + 4 * NTOK, lg, cnt, tile, out); break;
    case 5: phB_impl<5>(B16 + BOV[5], Tall, list + 5 * NTOK, lg, cnt, tile, out); break;
    default: phB_impl<6>(B16 + BOV[6], Tall, list + 6 * NTOK, lg, cnt, tile, out); break;
  }
}

extern "C" void kernel_launch(void* const* d_in, const int* in_sizes, int n_in,
                              void* d_out, int out_size, void* d_ws, size_t ws_size,
                              hipStream_t stream) {
  const float* x     = (const float*)d_in[0];
  const float* proto = (const float*)d_in[1];
  ExpPtrs p;
  for (int e = 0; e < NE; ++e) {
    p.A[e] = (const float*)d_in[2 + 2 * e];
    p.B[e] = (const float*)d_in[3 + 2 * e];
  }
  float* wsf  = (float*)d_ws;
  int*   wsi  = (int*)d_ws;
  short* B16  = (short*)(wsf + B16_OFF);
  short* AIMG = (short*)((char*)d_ws + AIMG_OFF_BYTES);
  short* Tall = (short*)((char*)d_ws + TALL_OFF_BYTES);
  float* out  = (float*)d_out;

  k_conv<<<dim3(16, NE), 256, 0, stream>>>(p, AIMG, B16, proto, wsf, wsi + CNT_OFF);
  k_simT<<<1024, 512, 0, stream>>>(x, AIMG, wsf, wsf + E0_OFF, wsf + PR1_OFF, Tall);
  k_pass<1><<<128, 256, 0, stream>>>(wsf + E0_OFF, wsf, wsf + PR1_OFF, 1024,
                                     wsf + PR2_OFF, nullptr, nullptr, nullptr);
  k_pass<2><<<128, 256, 0, stream>>>(wsf + E0_OFF, wsf, wsf + PR2_OFF, 128,
                                     wsf + PR3_OFF, nullptr, nullptr, nullptr);
  k_pass<3><<<128, 256, 0, stream>>>(wsf + E0_OFF, wsf, wsf + PR3_OFF, 128,
                                     nullptr, wsi + CNT_OFF, wsi + LIST_OFF, wsf + LG_OFF);
  k_phB<<<NBLK, 256, 0, stream>>>(B16, Tall, wsi + LIST_OFF, wsf + LG_OFF,
                                  wsi + CNT_OFF, out);
}

// Round 9
// 275.570 us; speedup vs baseline: 1.0005x; 1.0005x over previous
//
#include <hip/hip_runtime.h>
#include <math.h>

#define NTOK 32768
#define DIM  1024
#define NE   7
#define TROW 448   // T_all row width (DP-prefix padded), bf16

// ws layout (4-byte units up to B16; AIMG/TALL byte offsets). ws ~512 MB.
#define PN_OFF   0        // 7*1024 normalized prototypes (f32)
#define R1_OFF   7168
#define R2_OFF   7176
#define R3_OFF   7184
#define CNT_OFF  7192     // 8 ints
#define PR1_OFF  7200     // 512*8
#define PR2_OFF  23584    // 128*8
#define PR3_OFF  24608    // 128*8
#define E0_OFF   25632    // NTOK*8 exp(sim/kappa)
#define LG_OFF   287776   // NTOK: log(top-1 gate)
#define LIST_OFF 320544   // NE*NTOK ints
#define B16_OFF  754720   // bf16 B weights (padded cols)
#define AIMG_OFF_BYTES 3936384   // packed A image: 32 chunks * 12800 shorts = 800 KB
#define TALL_OFF_BYTES 4984960   // bf16 T_all [NTOK][448] = 29.4 MB
#define NBLK 2055

#define SEPS 1e-6f

typedef __attribute__((ext_vector_type(8))) short short8v;
typedef __attribute__((ext_vector_type(4))) float f32x4;

// per-expert geometry
constexpr int DV[7]   = {8, 16, 32, 48, 64, 96, 128};
constexpr int DPV[7]  = {32, 32, 32, 64, 64, 96, 128};   // K-padded
constexpr int DAPV[7] = {16, 16, 32, 48, 64, 96, 128};   // N-padded
constexpr int BOV[7]  = {0, 32768, 65536, 98304, 163840, 229376, 327680};
constexpr int APRE[7] = {0, 32, 64, 96, 160, 224, 320};  // DP-prefix col in T_all
constexpr int RSV[7]  = {0, 16, 32, 64, 112, 176, 272};  // DAP-prefix row in A-image
// T_all column base of global A-tile t (A rows 16t..16t+15), t = 0..24
constexpr int TCOL[25] = {0, 32, 64, 80, 96, 112, 128, 160, 176, 192, 208,
                          224, 240, 256, 272, 288, 304,
                          320, 336, 352, 368, 384, 400, 416, 432};

struct ExpPtrs { const float* A[NE]; const float* B[NE]; };

__device__ __forceinline__ short f2bf(float f) {
  union { float f; unsigned u; } v; v.f = f;
  return (short)((v.u + 0x7FFFu + ((v.u >> 16) & 1u)) >> 16);  // RNE
}

__device__ __forceinline__ float wsum(float v) {
  #pragma unroll
  for (int off = 32; off > 0; off >>= 1) v += __shfl_xor(v, off);
  return v;
}

__device__ __forceinline__ float dot4acc(float4 a, float4 b, float acc) {
  acc = fmaf(a.x, b.x, acc);
  acc = fmaf(a.y, b.y, acc);
  acc = fmaf(a.z, b.z, acc);
  acc = fmaf(a.w, b.w, acc);
  return acc;
}

// ---------------- K0: weights -> AIMG (packed fragment image) + B16; proto prep ------
// AIMG[c][row][q]: bf16x8 of A_global[row][c*32+q*8..], row pitch 32 shorts (64 B),
// chunk stride 12800 shorts. A-operand frag load = 1 KB coalesced per (tile, chunk).
__global__ __launch_bounds__(256) void k_conv(ExpPtrs p, short* __restrict__ AIMG,
                                              short* __restrict__ B16,
                                              const float* __restrict__ proto,
                                              float* __restrict__ wsf,
                                              int* __restrict__ counts) {
  const int e = blockIdx.y;
  const int tid = threadIdx.x;
  const int d = DV[e], dp = DPV[e], dap = DAPV[e], bo = BOV[e], rs = RSV[e];

  if (blockIdx.x == 0) {
    __shared__ float pred[4];
    if (e == 0 && tid < 8) counts[tid] = 0;
    const int w = tid >> 6, lane = tid & 63;
    float v4[4], ss = 0.f;
    #pragma unroll
    for (int i = 0; i < 4; ++i) {
      v4[i] = proto[e * DIM + tid + 256 * i];
      ss = fmaf(v4[i], v4[i], ss);
    }
    ss = wsum(ss);
    if (lane == 0) pred[w] = ss;
    __syncthreads();
    float tot = ((pred[0] + pred[1]) + pred[2]) + pred[3];
    float inv = 1.f / fmaxf(sqrtf(tot), 1e-12f);
    #pragma unroll
    for (int i = 0; i < 4; ++i)
      wsf[PN_OFF + e * DIM + tid + 256 * i] = v4[i] * inv;
  }

  const float* A = p.A[e];
  const float* B = p.B[e];
  const int t0 = blockIdx.x * 256 + tid;

  const int tot = dap * 128;  // rows x (32 chunks x 4 q)
  for (int i = t0; i < tot; i += 16 * 256) {
    int lr = i >> 7, rem = i & 127;
    int c = rem >> 2, q = rem & 3;
    short8v v = (short8v){0, 0, 0, 0, 0, 0, 0, 0};
    if (lr < d) {
      const float* src = A + (size_t)lr * DIM + c * 32 + q * 8;
      #pragma unroll
      for (int j = 0; j < 8; ++j) v[j] = f2bf(src[j]);
    }
    *(short8v*)&AIMG[c * 12800 + (rs + lr) * 32 + q * 8] = v;
  }

  short* Bd = B16 + bo;
  for (int i = t0; i < DIM * dp; i += 16 * 256) {
    int j = i / dp, r = i - j * dp;
    Bd[i] = (r < d) ? f2bf(B[(size_t)j * d + r]) : (short)0;
  }
}

// ---------------- K1: fused sim (f32) + T_all = x * A_all^T, barrier-free ----------
// 512 blocks x 256 thr. Wave w: tg=w>>1 -> tokens [n0+tg*32, +32) (two 16-groups),
// th=w&1 -> A-tile half (TH=0: tiles 0..12, TH=1: tiles 13..24).
// Swapped MFMA operands: D = [A-rows] x [tokens] -> lane holds 4 CONSECUTIVE T-cols
// of one token -> uint2 (8B) T-store. A-frags direct from L2-resident AIMG (no LDS).
// Sim (f32): TH=0 waves do experts 0..3; TH=1 do 4..6 + |x|^2.
template<int TH>
__device__ void simT_impl(const float* __restrict__ x,
                          const short* __restrict__ AIMG,
                          const float* __restrict__ PN,
                          float* __restrict__ e0,
                          float* __restrict__ pr1,
                          short* __restrict__ Tall,
                          float (*simS)[8], int n0) {
  constexpr int T0 = TH ? 13 : 0;
  constexpr int NT = TH ? 12 : 13;
  constexpr int ES = TH ? 4 : 0;
  constexpr int NEs = TH ? 3 : 4;
  const int tid = threadIdx.x;
  const int w = tid >> 6, lane = tid & 63, lo = lane & 15, hi = lane >> 4;
  const int tg = w >> 1;
  const int tokBase = n0 + tg * 32;

  const float* xpA = x + (size_t)(tokBase + lo) * DIM + hi * 8;
  const float* xpB = xpA + 16 * DIM;

  f32x4 acc[2][13];
  #pragma unroll
  for (int g = 0; g < 2; ++g)
    #pragma unroll
    for (int t = 0; t < 13; ++t) acc[g][t] = (f32x4){0.f, 0.f, 0.f, 0.f};
  float dk[2][4] = {{0.f, 0.f, 0.f, 0.f}, {0.f, 0.f, 0.f, 0.f}};
  float xxA = 0.f, xxB = 0.f;

  for (int c = 0; c < 32; ++c) {
    float4 a0 = *(const float4*)(xpA + c * 32);
    float4 a1 = *(const float4*)(xpA + c * 32 + 4);
    float4 b0 = *(const float4*)(xpB + c * 32);
    float4 b1 = *(const float4*)(xpB + c * 32 + 4);
    short8v afA, afB;
    afA[0] = f2bf(a0.x); afA[1] = f2bf(a0.y); afA[2] = f2bf(a0.z); afA[3] = f2bf(a0.w);
    afA[4] = f2bf(a1.x); afA[5] = f2bf(a1.y); afA[6] = f2bf(a1.z); afA[7] = f2bf(a1.w);
    afB[0] = f2bf(b0.x); afB[1] = f2bf(b0.y); afB[2] = f2bf(b0.z); afB[3] = f2bf(b0.w);
    afB[4] = f2bf(b1.x); afB[5] = f2bf(b1.y); afB[6] = f2bf(b1.z); afB[7] = f2bf(b1.w);

    #pragma unroll
    for (int k = 0; k < NEs; ++k) {
      const float* pp = PN + (ES + k) * DIM + c * 32 + hi * 8;
      float4 p0 = *(const float4*)pp;
      float4 p1 = *(const float4*)(pp + 4);
      dk[0][k] = dot4acc(a0, p0, dot4acc(a1, p1, dk[0][k]));
      dk[1][k] = dot4acc(b0, p0, dot4acc(b1, p1, dk[1][k]));
    }
    if (TH) {
      xxA = dot4acc(a0, a0, dot4acc(a1, a1, xxA));
      xxB = dot4acc(b0, b0, dot4acc(b1, b1, xxB));
    }
    const short* Ac = AIMG + c * 12800 + lo * 32 + hi * 8;
    #pragma unroll
    for (int tt = 0; tt < NT; ++tt) {
      short8v Af = *(const short8v*)(Ac + (T0 + tt) * 512);
      acc[0][tt] = __builtin_amdgcn_mfma_f32_16x16x32_bf16(Af, afA, acc[0][tt], 0, 0, 0);
      acc[1][tt] = __builtin_amdgcn_mfma_f32_16x16x32_bf16(Af, afB, acc[1][tt], 0, 0, 0);
    }
  }

  // T write: lane (lo,hi) reg j -> token (tokBase+g*16+lo), col TCOL[t]+hi*4+j
  #pragma unroll
  for (int tt = 0; tt < NT; ++tt) {
    const int colb = TCOL[T0 + tt] + hi * 4;
    #pragma unroll
    for (int g = 0; g < 2; ++g) {
      unsigned u0 = (unsigned short)f2bf(acc[g][tt][0]) |
                    ((unsigned)(unsigned short)f2bf(acc[g][tt][1]) << 16);
      unsigned u1 = (unsigned short)f2bf(acc[g][tt][2]) |
                    ((unsigned)(unsigned short)f2bf(acc[g][tt][3]) << 16);
      uint2 uv; uv.x = u0; uv.y = u1;
      *(uint2*)&Tall[(size_t)(tokBase + g * 16 + lo) * TROW + colb] = uv;
    }
  }

  // sim reduce across hi-slices
  #pragma unroll
  for (int g = 0; g < 2; ++g)
    #pragma unroll
    for (int k = 0; k < NEs; ++k) {
      dk[g][k] += __shfl_xor(dk[g][k], 16);
      dk[g][k] += __shfl_xor(dk[g][k], 32);
    }
  if (TH) {
    xxA += __shfl_xor(xxA, 16); xxA += __shfl_xor(xxA, 32);
    xxB += __shfl_xor(xxB, 16); xxB += __shfl_xor(xxB, 32);
  }
  if (hi == 0) {
    #pragma unroll
    for (int k = 0; k < NEs; ++k) {
      simS[tg * 32 + lo][ES + k]      = dk[0][k];
      simS[tg * 32 + 16 + lo][ES + k] = dk[1][k];
    }
    if (TH) {
      simS[tg * 32 + lo][7]      = xxA;
      simS[tg * 32 + 16 + lo][7] = xxB;
    }
  }
}

__global__ __launch_bounds__(256, 3) void k_simT(const float* __restrict__ x,
                                                 const short* __restrict__ AIMG,
                                                 const float* __restrict__ wsf,
                                                 float* __restrict__ e0,
                                                 float* __restrict__ pr1,
                                                 short* __restrict__ Tall) {
  __shared__ float simS[64][8];
  const int tid = threadIdx.x;
  const int n0 = blockIdx.x * 64;

  // zero Tall pad cols (16-31, 48-63, 144-159) for this block's 64 rows
  for (int i = tid; i < 64 * 48; i += 256) {
    int r = i / 48, c2 = i - r * 48;
    int col = (c2 < 16) ? (16 + c2) : ((c2 < 32) ? (32 + c2) : (112 + c2));
    Tall[(size_t)(n0 + r) * TROW + col] = 0;
  }

  if (((tid >> 6) & 1) == 0)
    simT_impl<0>(x, AIMG, wsf + PN_OFF, e0, pr1, Tall, simS, n0);
  else
    simT_impl<1>(x, AIMG, wsf + PN_OFF, e0, pr1, Tall, simS, n0);

  __syncthreads();
  if (tid < 64) {
    int n = n0 + tid;
    float nrm = fmaxf(sqrtf(simS[tid][7]), 1e-12f);
    float ev[8];
    #pragma unroll
    for (int k = 0; k < 7; ++k) ev[k] = expf((simS[tid][k] / nrm) / 0.1f);
    ev[7] = 0.f;
    *(float4*)&e0[(size_t)n * 8]     = make_float4(ev[0], ev[1], ev[2], ev[3]);
    *(float4*)&e0[(size_t)n * 8 + 4] = make_float4(ev[4], ev[5], ev[6], ev[7]);
    #pragma unroll
    for (int k = 0; k < 8; ++k) simS[tid][k] = ev[k];
  }
  __syncthreads();
  if (tid < 8) {
    float s = 0.f;
    for (int r = 0; r < 64; ++r) s += simS[r][tid];
    pr1[blockIdx.x * 8 + tid] = s;
  }
}

#define SUM7(l) (((((((l)[0] + (l)[1]) + (l)[2]) + (l)[3]) + (l)[4]) + (l)[5]) + (l)[6])

// ---------------- sinkhorn passes; each self-reduces prior partials ----------------
template<int DEPTH>
__global__ __launch_bounds__(256) void k_pass(const float* __restrict__ e0,
                                              float* __restrict__ wsf,
                                              const float* __restrict__ src, int nb,
                                              float* __restrict__ prOut,
                                              int* __restrict__ counts,
                                              int* __restrict__ list,
                                              float* __restrict__ lgv) {
  __shared__ float red2[8][33];
  __shared__ float Rcur[8];
  const int tid = threadIdx.x;
  {
    const int k = tid & 7, m = tid >> 3;
    float a = 0.f;
    for (int b = m; b < nb; b += 32) a += src[b * 8 + k];
    red2[k][m] = a;
    __syncthreads();
    if (tid < 8) {
      float s = 0.f;
      for (int mm = 0; mm < 32; ++mm) s += red2[tid][mm];
      Rcur[tid] = s;
      if (blockIdx.x == 0) {
        int roff = (DEPTH == 1) ? R1_OFF : (DEPTH == 2) ? R2_OFF : R3_OFF;
        wsf[roff + tid] = s;
      }
    }
    __syncthreads();
  }

  const int n = blockIdx.x * 256 + tid;
  float4 v0 = *(const float4*)(e0 + (size_t)n * 8);
  float4 v1 = *(const float4*)(e0 + (size_t)n * 8 + 4);
  float l[NE] = {v0.x, v0.y, v0.z, v0.w, v1.x, v1.y, v1.z};
  {
    const float* R1 = (DEPTH == 1) ? Rcur : (wsf + R1_OFF);
    #pragma unroll
    for (int k = 0; k < NE; ++k) l[k] = l[k] / (R1[k] + SEPS);
    float C = SUM7(l);
    #pragma unroll
    for (int k = 0; k < NE; ++k) l[k] = l[k] / (C + SEPS);
  }
  if constexpr (DEPTH >= 2) {
    const float* R2 = (DEPTH == 2) ? Rcur : (wsf + R2_OFF);
    #pragma unroll
    for (int k = 0; k < NE; ++k) l[k] = l[k] / (R2[k] + SEPS);
    float C = SUM7(l);
    #pragma unroll
    for (int k = 0; k < NE; ++k) l[k] = l[k] / (C + SEPS);
  }
  if constexpr (DEPTH >= 3) {
    const float* R3 = Rcur;
    #pragma unroll
    for (int k = 0; k < NE; ++k) l[k] = l[k] / (R3[k] + SEPS);
    float C = SUM7(l);
    #pragma unroll
    for (int k = 0; k < NE; ++k) l[k] = l[k] / (C + SEPS);
  }
  if constexpr (DEPTH == 3) {
    float best = l[0]; int be = 0;
    #pragma unroll
    for (int k = 1; k < NE; ++k) {
      if (l[k] > best) { best = l[k]; be = k; }
    }
    __shared__ int lcnt[8];
    __shared__ int wbase[4][8];
    __shared__ int gbase[8];
    const int w = tid >> 6, lane = tid & 63;
    if (tid < 8) lcnt[tid] = 0;
    __syncthreads();
    int rank = 0;
    #pragma unroll
    for (int k = 0; k < NE; ++k) {
      unsigned long long m = __ballot(be == k);
      if (lane == 0) wbase[w][k] = m ? atomicAdd(&lcnt[k], (int)__popcll(m)) : 0;
      if (be == k) rank = (int)__popcll(m & ((1ull << lane) - 1ull));
    }
    __syncthreads();
    if (tid < 8) gbase[tid] = lcnt[tid] ? atomicAdd(&counts[tid], lcnt[tid]) : 0;
    __syncthreads();
    int pos = gbase[be] + wbase[w][be] + rank;
    list[be * NTOK + pos] = n;
    lgv[n] = logf(best);
  } else {
    __shared__ float red[NE][256];
    #pragma unroll
    for (int k = 0; k < NE; ++k) red[k][tid] = l[k];
    __syncthreads();
    for (int off = 128; off > 0; off >>= 1) {
      if (tid < off) {
        #pragma unroll
        for (int k = 0; k < NE; ++k) red[k][tid] += red[k][tid + off];
      }
      __syncthreads();
    }
    if (tid < NE) prOut[blockIdx.x * 8 + tid] = red[tid][0];
  }
}

// ---------------- phase B: Y = T_all[tok, APRE_e..] * B^T + log(g) ----------------
__device__ __forceinline__ bool walk(int bid, const int* counts,
                                     int& e, int& tile, int& cnt) {
  int rem = bid; e = 0;
  while (true) {
    cnt = counts[e];
    int tiles = (cnt + 15) >> 4;
    if (rem < tiles) { tile = rem; return true; }
    rem -= tiles;
    if (++e == NE) return false;
  }
}

template<int E>
__device__ void phB_impl(const short* __restrict__ Bp,
                         const short* __restrict__ Tall,
                         const int* __restrict__ list_e,
                         const float* __restrict__ lg,
                         int cnt, int tile, float* __restrict__ out) {
  constexpr int DP = DPV[E];
  constexpr int KS2 = DP / 32;
  const int tid = threadIdx.x;
  const int w = tid >> 6, lane = tid & 63;
  const int lo = lane & 15, hi = lane >> 4;
  const int m0 = tile * 16;

  const int myTok = list_e[min(m0 + lo, cnt - 1)];
  short8v tf[KS2];
  #pragma unroll
  for (int ks = 0; ks < KS2; ++ks)
    tf[ks] = *(const short8v*)(Tall + (size_t)myTok * TROW + APRE[E] + ks * 32 + hi * 8);

  int tok[4]; float lgvr[4];
  #pragma unroll
  for (int j = 0; j < 4; ++j) {
    tok[j] = list_e[min(m0 + hi * 4 + j, cnt - 1)];
    lgvr[j] = lg[tok[j]];
  }

  const short* BpL = Bp + (size_t)(w * 256 + lo) * DP + hi * 8;
  #pragma unroll 1
  for (int nt = 0; nt < 16; ++nt) {
    f32x4 acc = (f32x4){0.f, 0.f, 0.f, 0.f};
    #pragma unroll
    for (int ks = 0; ks < KS2; ++ks) {
      short8v bf = *(const short8v*)(BpL + (size_t)nt * 16 * DP + ks * 32);
      acc = __builtin_amdgcn_mfma_f32_16x16x32_bf16(tf[ks], bf, acc, 0, 0, 0);
    }
    #pragma unroll
    for (int j = 0; j < 4; ++j)
      out[(size_t)tok[j] * DIM + w * 256 + nt * 16 + lo] = acc[j] + lgvr[j];
  }
}

__global__ __launch_bounds__(256, 8) void k_phB(const short* __restrict__ B16,
                                                const short* __restrict__ Tall,
                                                const int* __restrict__ list,
                                                const float* __restrict__ lg,
                                                const int* __restrict__ counts,
                                                float* __restrict__ out) {
  int bid = ((int)blockIdx.x * 1024) % NBLK;  // coprime stride: spread heavy experts
  int e, tile, cnt;
  if (!walk(bid, counts, e, tile, cnt)) return;
  switch (e) {
    case 0: phB_impl<0>(B16 + BOV[0], Tall, list + 0 * NTOK, lg, cnt, tile, out); break;
    case 1: phB_impl<1>(B16 + BOV[1], Tall, list + 1 * NTOK, lg, cnt, tile, out); break;
    case 2: phB_impl<2>(B16 + BOV[2], Tall, list + 2 * NTOK, lg, cnt, tile, out); break;
    case 3: phB_impl<3>(B16 + BOV[3], Tall, list + 3 * NTOK, lg, cnt, tile, out); break;
    case 4: phB_impl<4>(B16 + BOV[4], Tall, list + 4 * NTOK, lg, cnt, tile, out); break;
    case 5: phB_impl<5>(B16 + BOV[5], Tall, list + 5 * NTOK, lg, cnt, tile, out); break;
    default: phB_impl<6>(B16 + BOV[6], Tall, list + 6 * NTOK, lg, cnt, tile, out); break;
  }
}

extern "C" void kernel_launch(void* const* d_in, const int* in_sizes, int n_in,
                              void* d_out, int out_size, void* d_ws, size_t ws_size,
                              hipStream_t stream) {
  const float* x     = (const float*)d_in[0];
  const float* proto = (const float*)d_in[1];
  ExpPtrs p;
  for (int e = 0; e < NE; ++e) {
    p.A[e] = (const float*)d_in[2 + 2 * e];
    p.B[e] = (const float*)d_in[3 + 2 * e];
  }
  float* wsf  = (float*)d_ws;
  int*   wsi  = (int*)d_ws;
  short* B16  = (short*)(wsf + B16_OFF);
  short* AIMG = (short*)((char*)d_ws + AIMG_OFF_BYTES);
  short* Tall = (short*)((char*)d_ws + TALL_OFF_BYTES);
  float* out  = (float*)d_out;

  k_conv<<<dim3(16, NE), 256, 0, stream>>>(p, AIMG, B16, proto, wsf, wsi + CNT_OFF);
  k_simT<<<512, 256, 0, stream>>>(x, AIMG, wsf, wsf + E0_OFF, wsf + PR1_OFF, Tall);
  k_pass<1><<<128, 256, 0, stream>>>(wsf + E0_OFF, wsf, wsf + PR1_OFF, 512,
                                     wsf + PR2_OFF, nullptr, nullptr, nullptr);
  k_pass<2><<<128, 256, 0, stream>>>(wsf + E0_OFF, wsf, wsf + PR2_OFF, 128,
                                     wsf + PR3_OFF, nullptr, nullptr, nullptr);
  k_pass<3><<<128, 256, 0, stream>>>(wsf + E0_OFF, wsf, wsf + PR3_OFF, 128,
                                     nullptr, wsi + CNT_OFF, wsi + LIST_OFF, wsf + LG_OFF);
  k_phB<<<NBLK, 256, 0, stream>>>(B16, Tall, wsi + LIST_OFF, wsf + LG_OFF,
                                  wsi + CNT_OFF, out);
}